// Round 5
// baseline (481.758 us; speedup 1.0000x reference)
//
#include <hip/hip_runtime.h>
#include <hip/hip_bf16.h>
#include <math.h>

#define NROWS 8192
#define DDIM  1024
#define BT    128
#define BKB   128      // K elements (bytes) per tile in fp8
#define NBLK  (NROWS / BT)
#define MARGIN 0.3f
#define INV256 0.00390625f

typedef __attribute__((ext_vector_type(4))) float  f32x4;
typedef __attribute__((ext_vector_type(8))) __bf16 bf16x8;
typedef __attribute__((ext_vector_type(4))) int    i32x4;
typedef __attribute__((ext_vector_type(8))) int    i32x8;

__device__ __forceinline__ unsigned f2bf_bits(float f) {
  unsigned u = __float_as_uint(f);
  u += 0x7fffu + ((u >> 16) & 1u);   // RNE
  return u >> 16;
}

// ============================ FAST PATH (MX-fp8) ============================
// Kernel A: row-norm + fp8 e4m3 quantize of 16*xn; zeroes rowsum/colsum+counter.
__global__ __launch_bounds__(256) void normconv8_kernel(const float* __restrict__ x,
                                                        const float* __restrict__ y,
                                                        unsigned int* __restrict__ xq,
                                                        unsigned int* __restrict__ yq,
                                                        float* __restrict__ zero_base,
                                                        unsigned int* __restrict__ counter) {
  if (blockIdx.x < 16) {  // 16 blk * 256 thr * float4 = 16384 floats (rowsum+colsum)
    ((float4*)zero_base)[blockIdx.x * 256 + threadIdx.x] = (float4){0.f, 0.f, 0.f, 0.f};
  }
  if (blockIdx.x == 16 && threadIdx.x == 0) *counter = 0u;
  int wid  = blockIdx.x * 4 + (threadIdx.x >> 6);   // one wave per row
  int lane = threadIdx.x & 63;
  const float* src;
  unsigned int* dst;
  int row;
  if (wid < NROWS) { src = x; dst = xq; row = wid; }
  else             { src = y; dst = yq; row = wid - NROWS; }
  const float4* p = (const float4*)(src + (size_t)row * DDIM);
  float4 v[4];
  float s = 0.f;
#pragma unroll
  for (int a = 0; a < 4; ++a) {
    v[a] = p[a * 64 + lane];
    s = fmaf(v[a].x, v[a].x, s); s = fmaf(v[a].y, v[a].y, s);
    s = fmaf(v[a].z, v[a].z, s); s = fmaf(v[a].w, v[a].w, s);
  }
#pragma unroll
  for (int m = 1; m < 64; m <<= 1) s += __shfl_xor(s, m, 64);
  // scale by 16 into fp8 to stay clear of e4m3 denormals; undone in epilogue
  float inv = 16.0f / fmaxf(sqrtf(s), 1e-8f);
  unsigned int* d4 = dst + (size_t)row * (DDIM / 4);
#pragma unroll
  for (int a = 0; a < 4; ++a) {
    int w = __builtin_amdgcn_cvt_pk_fp8_f32(v[a].x * inv, v[a].y * inv, 0, false);
    w     = __builtin_amdgcn_cvt_pk_fp8_f32(v[a].z * inv, v[a].w * inv, w, true);
    d4[a * 64 + lane] = (unsigned int)w;
  }
}

// Kernel B: MX-fp8 GEMM. A-frags straight from global (TA pipe, L1-resident
// 16KB/iter working set); B staged via global_load_lds into XOR-swizzled LDS.
// Fused exp+row/col reduce+diag epilogue, then last-block-done finalize.
__global__ __launch_bounds__(256) void gemm_mx_kernel(const unsigned char* __restrict__ xq,
                                                      const unsigned char* __restrict__ yq,
                                                      float* __restrict__ rowsum,
                                                      float* __restrict__ colsum,
                                                      float* __restrict__ diagv,
                                                      unsigned int* __restrict__ counter,
                                                      float* __restrict__ out) {
  __shared__ alignas(16) unsigned char Bs[BT * BKB];  // 16 KB
  __shared__ float red_row[BT];
  __shared__ float red_col[BT];
  __shared__ int lastflag;

  const int tid  = threadIdx.x;
  const int bi   = blockIdx.y;
  const int bj   = blockIdx.x;
  const int lane = tid & 63;
  const int wave = tid >> 6;
  const int wr   = wave >> 1, wc = wave & 1;
  const int quad = lane >> 4, l15 = lane & 15;

  if (tid < BT) red_row[tid] = 0.f; else red_col[tid - BT] = 0.f;

  // B staging: lane l -> local row (l>>3); SOURCE 16B-group (l&7)^(l>>3) so
  // physical LDS group (l&7) holds logical group g = p ^ (row&7) (bank swizzle).
  const int r_l = lane >> 3;
  const int cg  = (lane & 7) ^ r_l;
  const unsigned char* gb = yq + (size_t)(bj * BT + wave * 32 + r_l) * DDIM + cg * 16;

  // A-frag row pointers (global, per lane): row = bi*128 + wr*64 + f*16 + l15,
  // k = quad*32 + j  ->  32 contiguous bytes at +quad*32.
  const unsigned char* arow[4];
#pragma unroll
  for (int f = 0; f < 4; ++f)
    arow[f] = xq + (size_t)(bi * BT + wr * 64 + f * 16 + l15) * DDIM + quad * 32;

  f32x4 acc[4][4];
#pragma unroll
  for (int i = 0; i < 4; ++i)
#pragma unroll
    for (int j = 0; j < 4; ++j) acc[i][j] = (f32x4){0.f, 0.f, 0.f, 0.f};

  const int r7 = l15 & 7;
  for (int k0 = 0; k0 < DDIM; k0 += BKB) {
#pragma unroll
    for (int a = 0; a < 4; ++a) {
      __builtin_amdgcn_global_load_lds(
          (const __attribute__((address_space(1))) unsigned int*)(gb + (size_t)a * 8 * DDIM + k0),
          (__attribute__((address_space(3))) unsigned int*)&Bs[(wave * 32 + a * 8) * BKB],
          16, 0, 0);
    }
    // A frags from global while staging is in flight
    i32x8 af[4];
#pragma unroll
    for (int f = 0; f < 4; ++f) {
      i32x4 alo = *(const i32x4*)(arow[f] + k0);
      i32x4 ahi = *(const i32x4*)(arow[f] + k0 + 16);
      af[f] = (i32x8){alo.x, alo.y, alo.z, alo.w, ahi.x, ahi.y, ahi.z, ahi.w};
    }
    __syncthreads();
    i32x8 bf[4];
#pragma unroll
    for (int f = 0; f < 4; ++f) {
      const unsigned char* rb = &Bs[(wc * 64 + f * 16 + l15) * BKB];
      i32x4 blo = *(const i32x4*)(rb + (((quad * 2 + 0) ^ r7) * 16));
      i32x4 bhi = *(const i32x4*)(rb + (((quad * 2 + 1) ^ r7) * 16));
      bf[f] = (i32x8){blo.x, blo.y, blo.z, blo.w, bhi.x, bhi.y, bhi.z, bhi.w};
    }
#pragma unroll
    for (int fr = 0; fr < 4; ++fr)
#pragma unroll
      for (int fc = 0; fc < 4; ++fc)
        acc[fr][fc] = __builtin_amdgcn_mfma_scale_f32_16x16x128_f8f6f4(
            af[fr], bf[fc], acc[fr][fc],
            0, 0,                     // cbsz=FP8(e4m3), blgp=FP8(e4m3)
            0, 0x7F7F7F7F,            // opsel_a, scale_a (e8m0 127 = 1.0)
            0, 0x7F7F7F7F);           // opsel_b, scale_b
    __syncthreads();
  }

  // ---- epilogue (R1-validated mapping; acc * 1/256 undoes the 16*16 prescale)
  if (bi == bj && wr == wc && (l15 >> 2) == quad) {
    int r = l15 & 3;
#pragma unroll
    for (int f = 0; f < 4; ++f)
      __hip_atomic_store(&diagv[bi * BT + wr * 64 + f * 16 + l15],
                         acc[f][f][r] * INV256,
                         __ATOMIC_RELAXED, __HIP_MEMORY_SCOPE_AGENT);
  }

  float racc[4][4];
  float cacc[4];
#pragma unroll
  for (int i = 0; i < 4; ++i) {
    cacc[i] = 0.f;
#pragma unroll
    for (int j = 0; j < 4; ++j) racc[i][j] = 0.f;
  }
#pragma unroll
  for (int fr = 0; fr < 4; ++fr)
#pragma unroll
    for (int fc = 0; fc < 4; ++fc) {
      f32x4 v = acc[fr][fc];
#pragma unroll
      for (int r = 0; r < 4; ++r) {
        float e = __expf(v[r] * INV256);
        racc[fr][r] += e;
        cacc[fc]    += e;
      }
    }
#pragma unroll
  for (int m = 1; m <= 8; m <<= 1)
#pragma unroll
    for (int fr = 0; fr < 4; ++fr)
#pragma unroll
      for (int r = 0; r < 4; ++r) racc[fr][r] += __shfl_xor(racc[fr][r], m, 64);
  if (l15 == 0)
#pragma unroll
    for (int fr = 0; fr < 4; ++fr)
#pragma unroll
      for (int r = 0; r < 4; ++r)
        atomicAdd(&red_row[wr * 64 + fr * 16 + quad * 4 + r], racc[fr][r]);
#pragma unroll
  for (int m = 16; m <= 32; m <<= 1)
#pragma unroll
    for (int fc = 0; fc < 4; ++fc) cacc[fc] += __shfl_xor(cacc[fc], m, 64);
  if (quad == 0)
#pragma unroll
    for (int fc = 0; fc < 4; ++fc)
      atomicAdd(&red_col[wc * 64 + fc * 16 + l15], cacc[fc]);

  __syncthreads();
  if (tid < BT) atomicAdd(&rowsum[bi * BT + tid], red_row[tid]);
  else          atomicAdd(&colsum[bj * BT + (tid - BT)], red_col[tid - BT]);

  // ---- last-block-done finalize (device-scope counter, agent-scope reads) --
  __threadfence();                       // release our atomics before count
  if (tid == 0) {
    unsigned int c = atomicAdd(counter, 1u);
    lastflag = (c == (unsigned int)(NBLK * NBLK - 1));
  }
  __syncthreads();
  if (lastflag) {
    __threadfence();                     // acquire all blocks' results
    float s = 0.f;
    for (int i = tid; i < NROWS; i += 256) {
      float d  = __hip_atomic_load(&diagv[i],  __ATOMIC_RELAXED, __HIP_MEMORY_SCOPE_AGENT);
      float rs = __hip_atomic_load(&rowsum[i], __ATOMIC_RELAXED, __HIP_MEMORY_SCOPE_AGENT);
      float cs = __hip_atomic_load(&colsum[i], __ATOMIC_RELAXED, __HIP_MEMORY_SCOPE_AGENT);
      float ed = __expf(d);
      float m1 = __expf(d - MARGIN);
      s += __logf((m1 + (rs - ed)) / m1) + __logf((m1 + (cs - ed)) / m1);
    }
#pragma unroll
    for (int m = 1; m < 64; m <<= 1) s += __shfl_xor(s, m, 64);
    if ((tid & 63) == 0) red_row[tid >> 6] = s;
    __syncthreads();
    if (tid == 0)
      out[0] = (red_row[0] + red_row[1] + red_row[2] + red_row[3]) / (float)NROWS;
  }
}

// ============================ FALLBACK PATH (R1, known-good) ================
__global__ __launch_bounds__(256) void norm_kernel(const float* __restrict__ x,
                                                   const float* __restrict__ y,
                                                   float* __restrict__ invn) {
  int wid  = (int)((blockIdx.x * blockDim.x + threadIdx.x) >> 6);
  int lane = threadIdx.x & 63;
  const float* src = (wid < NROWS) ? x : y;
  int row = (wid < NROWS) ? wid : (wid - NROWS);
  const float4* p = (const float4*)(src + (size_t)row * DDIM);
  float s = 0.f;
#pragma unroll
  for (int a = 0; a < 4; ++a) {
    float4 v = p[a * 64 + lane];
    s = fmaf(v.x, v.x, s); s = fmaf(v.y, v.y, s);
    s = fmaf(v.z, v.z, s); s = fmaf(v.w, v.w, s);
  }
#pragma unroll
  for (int m = 1; m < 64; m <<= 1) s += __shfl_xor(s, m, 64);
  if (lane == 0) invn[wid] = 1.0f / fmaxf(sqrtf(s), 1e-8f);
}

__global__ __launch_bounds__(256) void gemm_kernel(const float* __restrict__ x,
                                                   const float* __restrict__ y,
                                                   const float* __restrict__ invn,
                                                   float* __restrict__ rowsum,
                                                   float* __restrict__ colsum,
                                                   float* __restrict__ diagv) {
  __shared__ alignas(16) unsigned short As[BT * 64];
  __shared__ alignas(16) unsigned short Bs[BT * 64];
  __shared__ float red_row[BT];
  __shared__ float red_col[BT];

  const int tid  = threadIdx.x;
  const int bi   = blockIdx.y;
  const int bj   = blockIdx.x;
  const int lane = tid & 63;
  const int wave = tid >> 6;
  const int wr   = wave >> 1, wc = wave & 1;
  const int quad = lane >> 4, l15 = lane & 15;
  const int srow = tid >> 4;
  const int sc4  = tid & 15;

  if (tid < BT) red_row[tid] = 0.f; else red_col[tid - BT] = 0.f;

  float ainv[8], binv[8];
#pragma unroll
  for (int a = 0; a < 8; ++a) {
    ainv[a] = invn[bi * BT + a * 16 + srow];
    binv[a] = invn[NROWS + bj * BT + a * 16 + srow];
  }

  f32x4 acc[4][4];
#pragma unroll
  for (int i = 0; i < 4; ++i)
#pragma unroll
    for (int j = 0; j < 4; ++j) acc[i][j] = (f32x4){0.f, 0.f, 0.f, 0.f};

  for (int k0 = 0; k0 < DDIM; k0 += 64) {
#pragma unroll
    for (int a = 0; a < 8; ++a) {
      int row = a * 16 + srow;
      float4 va = *(const float4*)(x + (size_t)(bi * BT + row) * DDIM + k0 + sc4 * 4);
      float4 vb = *(const float4*)(y + (size_t)(bj * BT + row) * DDIM + k0 + sc4 * 4);
      float sa = ainv[a], sb = binv[a];
      unsigned long long pa =
          (unsigned long long)f2bf_bits(va.x * sa) |
          ((unsigned long long)f2bf_bits(va.y * sa) << 16) |
          ((unsigned long long)f2bf_bits(va.z * sa) << 32) |
          ((unsigned long long)f2bf_bits(va.w * sa) << 48);
      unsigned long long pb =
          (unsigned long long)f2bf_bits(vb.x * sb) |
          ((unsigned long long)f2bf_bits(vb.y * sb) << 16) |
          ((unsigned long long)f2bf_bits(vb.z * sb) << 32) |
          ((unsigned long long)f2bf_bits(vb.w * sb) << 48);
      *(unsigned long long*)&As[row * 64 + sc4 * 4] = pa;
      *(unsigned long long*)&Bs[row * 64 + sc4 * 4] = pb;
    }
    __syncthreads();
#pragma unroll
    for (int kk = 0; kk < 64; kk += 32) {
      bf16x8 af[4], bf[4];
#pragma unroll
      for (int f = 0; f < 4; ++f) {
        af[f] = *(const bf16x8*)&As[(wr * 64 + f * 16 + l15) * 64 + kk + quad * 8];
        bf[f] = *(const bf16x8*)&Bs[(wc * 64 + f * 16 + l15) * 64 + kk + quad * 8];
      }
#pragma unroll
      for (int fr = 0; fr < 4; ++fr)
#pragma unroll
        for (int fc = 0; fc < 4; ++fc)
          acc[fr][fc] = __builtin_amdgcn_mfma_f32_16x16x32_bf16(af[fr], bf[fc], acc[fr][fc], 0, 0, 0);
    }
    __syncthreads();
  }

  if (bi == bj && wr == wc && (l15 >> 2) == quad) {
    int r = l15 & 3;
#pragma unroll
    for (int f = 0; f < 4; ++f)
      diagv[bi * BT + wr * 64 + f * 16 + l15] = acc[f][f][r];
  }

  float racc[4][4];
  float cacc[4];
#pragma unroll
  for (int i = 0; i < 4; ++i) {
    cacc[i] = 0.f;
#pragma unroll
    for (int j = 0; j < 4; ++j) racc[i][j] = 0.f;
  }
#pragma unroll
  for (int fr = 0; fr < 4; ++fr)
#pragma unroll
    for (int fc = 0; fc < 4; ++fc) {
      f32x4 v = acc[fr][fc];
#pragma unroll
      for (int r = 0; r < 4; ++r) {
        float e = __expf(v[r]);
        racc[fr][r] += e;
        cacc[fc]    += e;
      }
    }
#pragma unroll
  for (int m = 1; m <= 8; m <<= 1)
#pragma unroll
    for (int fr = 0; fr < 4; ++fr)
#pragma unroll
      for (int r = 0; r < 4; ++r) racc[fr][r] += __shfl_xor(racc[fr][r], m, 64);
  if (l15 == 0)
#pragma unroll
    for (int fr = 0; fr < 4; ++fr)
#pragma unroll
      for (int r = 0; r < 4; ++r)
        atomicAdd(&red_row[wr * 64 + fr * 16 + quad * 4 + r], racc[fr][r]);
#pragma unroll
  for (int m = 16; m <= 32; m <<= 1)
#pragma unroll
    for (int fc = 0; fc < 4; ++fc) cacc[fc] += __shfl_xor(cacc[fc], m, 64);
  if (quad == 0)
#pragma unroll
    for (int fc = 0; fc < 4; ++fc)
      atomicAdd(&red_col[wc * 64 + fc * 16 + l15], cacc[fc]);

  __syncthreads();
  if (tid < BT) atomicAdd(&rowsum[bi * BT + tid], red_row[tid]);
  else          atomicAdd(&colsum[bj * BT + (tid - BT)], red_col[tid - BT]);
}

__global__ __launch_bounds__(1024) void finalize_kernel(const float* __restrict__ rowsum,
                                                        const float* __restrict__ colsum,
                                                        const float* __restrict__ diagv,
                                                        float* __restrict__ out) {
  float s = 0.f;
  for (int i = threadIdx.x; i < NROWS; i += 1024) {
    float d  = diagv[i];
    float ed = __expf(d);
    float m1 = __expf(d - MARGIN);
    float negR = rowsum[i] - ed;
    float negC = colsum[i] - ed;
    s += __logf((m1 + negR) / m1) + __logf((m1 + negC) / m1);
  }
  __shared__ float red[16];
#pragma unroll
  for (int m = 1; m < 64; m <<= 1) s += __shfl_xor(s, m, 64);
  if ((threadIdx.x & 63) == 0) red[threadIdx.x >> 6] = s;
  __syncthreads();
  if (threadIdx.x < 64) {
    float v = (threadIdx.x < 16) ? red[threadIdx.x] : 0.f;
#pragma unroll
    for (int m = 1; m < 16; m <<= 1) v += __shfl_xor(v, m, 64);
    if (threadIdx.x == 0) out[0] = v / (float)NROWS;
  }
}

extern "C" void kernel_launch(void* const* d_in, const int* in_sizes, int n_in,
                              void* d_out, int out_size, void* d_ws, size_t ws_size,
                              hipStream_t stream) {
  const float* x = (const float*)d_in[0];
  const float* y = (const float*)d_in[1];
  float* out = (float*)d_out;
  char* ws = (char*)d_ws;

  const size_t q_bytes = (size_t)NROWS * DDIM;               // 8 MB each (fp8)
  const size_t need_fast = 2 * q_bytes + 3 * NROWS * 4 + 64; // ~16 MB + 96 KB

  if (ws_size >= need_fast) {
    unsigned int* xq = (unsigned int*)ws;
    unsigned int* yq = (unsigned int*)(ws + q_bytes);
    float* rowsum = (float*)(ws + 2 * q_bytes);
    float* colsum = rowsum + NROWS;
    float* diagv  = colsum + NROWS;
    unsigned int* counter = (unsigned int*)(diagv + NROWS);
    normconv8_kernel<<<dim3((2 * NROWS) / 4), 256, 0, stream>>>(x, y, xq, yq, rowsum, counter);
    gemm_mx_kernel<<<dim3(NBLK, NBLK), 256, 0, stream>>>(
        (const unsigned char*)xq, (const unsigned char*)yq, rowsum, colsum, diagv, counter, out);
  } else {
    float* invn   = (float*)ws;
    float* rowsum = (float*)(ws + 16384 * 4);
    float* colsum = rowsum + NROWS;
    float* diagv  = colsum + NROWS;
    hipMemsetAsync(rowsum, 0, 2 * NROWS * sizeof(float), stream);
    norm_kernel<<<dim3((2 * NROWS) / 4 / 64), 256, 0, stream>>>(x, y, invn);
    gemm_kernel<<<dim3(NROWS / BT, NROWS / BT), 256, 0, stream>>>(x, y, invn, rowsum, colsum, diagv);
    finalize_kernel<<<dim3(1), 1024, 0, stream>>>(rowsum, colsum, diagv, out);
  }
}

// Round 6
// 411.710 us; speedup vs baseline: 1.1701x; 1.1701x over previous
//
#include <hip/hip_runtime.h>
#include <hip/hip_bf16.h>
#include <math.h>

#define NROWS 8192
#define DDIM  1024
#define BT    128
#define BKB   128      // K elements (bytes) per tile in fp8
#define NBLK  (NROWS / BT)
#define MARGIN 0.3f
#define INV256 0.00390625f

typedef __attribute__((ext_vector_type(4))) float  f32x4;
typedef __attribute__((ext_vector_type(8))) __bf16 bf16x8;
typedef __attribute__((ext_vector_type(4))) int    i32x4;
typedef __attribute__((ext_vector_type(8))) int    i32x8;

__device__ __forceinline__ unsigned f2bf_bits(float f) {
  unsigned u = __float_as_uint(f);
  u += 0x7fffu + ((u >> 16) & 1u);   // RNE
  return u >> 16;
}

// ============================ FAST PATH (MX-fp8) ============================
// Kernel A: row-norm + fp8 e4m3 quantize of 16*xn.
//  - x rows -> xqF, packed in frag-native 2 KB tiles [t=row/16][k0b=k/128]:
//      byte (row r, k) at ((t*8+k0b)*2048) + ((k>>4)&1)*1024 + ((k>>5)&3)*256
//                        + (r&15)*16 + (k&15)
//    so a gemm A-frag load j is dense: tile_base + j*1024 + lane*16.
//  - y rows -> yq, plain row-major (for LDS DMA staging).
// Also zeroes rowsum/colsum and the completion counter.
__global__ __launch_bounds__(256) void normconv8_kernel(const float* __restrict__ x,
                                                        const float* __restrict__ y,
                                                        unsigned int* __restrict__ xqF,
                                                        unsigned int* __restrict__ yq,
                                                        float* __restrict__ zero_base,
                                                        unsigned int* __restrict__ counter) {
  if (blockIdx.x < 16) {  // 16 blk * 256 thr * float4 = 16384 floats (rowsum+colsum)
    ((float4*)zero_base)[blockIdx.x * 256 + threadIdx.x] = (float4){0.f, 0.f, 0.f, 0.f};
  }
  if (blockIdx.x == 16 && threadIdx.x == 0) *counter = 0u;
  int wid  = blockIdx.x * 4 + (threadIdx.x >> 6);   // one wave per row
  int lane = threadIdx.x & 63;
  bool isx = (wid < NROWS);
  const float* src = isx ? x : y;
  int row = isx ? wid : (wid - NROWS);
  const float4* p = (const float4*)(src + (size_t)row * DDIM);
  float4 v[4];
  float s = 0.f;
#pragma unroll
  for (int a = 0; a < 4; ++a) {
    v[a] = p[a * 64 + lane];
    s = fmaf(v[a].x, v[a].x, s); s = fmaf(v[a].y, v[a].y, s);
    s = fmaf(v[a].z, v[a].z, s); s = fmaf(v[a].w, v[a].w, s);
  }
#pragma unroll
  for (int m = 1; m < 64; m <<= 1) s += __shfl_xor(s, m, 64);
  // scale by 16 into fp8 to stay clear of e4m3 denormals; undone in epilogue
  float inv = 16.0f / fmaxf(sqrtf(s), 1e-8f);
  if (isx) {
    // packed write: lane l, iter a holds word at k = a*256 + l*4
    int t = row >> 4;
    int r15 = row & 15;
#pragma unroll
    for (int a = 0; a < 4; ++a) {
      int w = __builtin_amdgcn_cvt_pk_fp8_f32(v[a].x * inv, v[a].y * inv, 0, false);
      w     = __builtin_amdgcn_cvt_pk_fp8_f32(v[a].z * inv, v[a].w * inv, w, true);
      int k0b = a * 2 + (lane >> 5);
      int j   = (lane >> 2) & 1;
      int q   = (lane >> 3) & 3;
      size_t db = ((size_t)(t * 8 + k0b) << 11) + (j << 10) + (q << 8)
                  + (r15 << 4) + ((lane & 3) << 2);
      xqF[db >> 2] = (unsigned int)w;
    }
  } else {
    unsigned int* d4 = yq + (size_t)row * (DDIM / 4);
#pragma unroll
    for (int a = 0; a < 4; ++a) {
      int w = __builtin_amdgcn_cvt_pk_fp8_f32(v[a].x * inv, v[a].y * inv, 0, false);
      w     = __builtin_amdgcn_cvt_pk_fp8_f32(v[a].z * inv, v[a].w * inv, w, true);
      d4[a * 64 + lane] = (unsigned int)w;
    }
  }
}

// Kernel B: MX-fp8 GEMM. A-frags coalesced from packed global tiles (TA pipe,
// L2-resident); B staged via global_load_lds into XOR-swizzled LDS (LDS pipe).
// Fused exp+row/col reduce+diag epilogue, then last-block-done finalize.
__global__ __launch_bounds__(256) void gemm_mx_kernel(const unsigned char* __restrict__ xqF,
                                                      const unsigned char* __restrict__ yq,
                                                      float* __restrict__ rowsum,
                                                      float* __restrict__ colsum,
                                                      float* __restrict__ diagv,
                                                      unsigned int* __restrict__ counter,
                                                      float* __restrict__ out) {
  __shared__ alignas(16) unsigned char Bs[BT * BKB];  // 16 KB
  __shared__ float red_row[BT];
  __shared__ float red_col[BT];
  __shared__ int lastflag;

  const int tid  = threadIdx.x;
  const int bi   = blockIdx.y;
  const int bj   = blockIdx.x;
  const int lane = tid & 63;
  const int wave = tid >> 6;
  const int wr   = wave >> 1, wc = wave & 1;
  const int quad = lane >> 4, l15 = lane & 15;

  if (tid < BT) red_row[tid] = 0.f; else red_col[tid - BT] = 0.f;

  // B staging: lane l -> local row (l>>3); SOURCE 16B-group (l&7)^(l>>3) so
  // physical LDS group (l&7) holds logical group g = p ^ (row&7) (bank swizzle).
  const int r_l = lane >> 3;
  const int cg  = (lane & 7) ^ r_l;
  const unsigned char* gb = yq + (size_t)(bj * BT + wave * 32 + r_l) * DDIM + cg * 16;

  // A frag tile bases: tile t = bi*8 + wr*4 + f; per k0b advance 2 KB.
  const unsigned char* gaf[4];
#pragma unroll
  for (int f = 0; f < 4; ++f)
    gaf[f] = xqF + ((size_t)(bi * 8 + wr * 4 + f) << 14) + lane * 16;

  f32x4 acc[4][4];
#pragma unroll
  for (int i = 0; i < 4; ++i)
#pragma unroll
    for (int j = 0; j < 4; ++j) acc[i][j] = (f32x4){0.f, 0.f, 0.f, 0.f};

  const int r7 = l15 & 7;
  for (int k0 = 0; k0 < DDIM; k0 += BKB) {
    const size_t kofs = (size_t)(k0 >> 7) << 11;
#pragma unroll
    for (int a = 0; a < 4; ++a) {
      __builtin_amdgcn_global_load_lds(
          (const __attribute__((address_space(1))) unsigned int*)(gb + (size_t)a * 8 * DDIM + k0),
          (__attribute__((address_space(3))) unsigned int*)&Bs[(wave * 32 + a * 8) * BKB],
          16, 0, 0);
    }
    // coalesced A frag loads (dense 1 KB per instruction)
    i32x8 af[4];
#pragma unroll
    for (int f = 0; f < 4; ++f) {
      i32x4 alo = *(const i32x4*)(gaf[f] + kofs);          // k = quad*32 + 0..15
      i32x4 ahi = *(const i32x4*)(gaf[f] + kofs + 1024);   // k = quad*32 + 16..31
      af[f] = (i32x8){alo.x, alo.y, alo.z, alo.w, ahi.x, ahi.y, ahi.z, ahi.w};
    }
    __syncthreads();
    i32x8 bf[4];
#pragma unroll
    for (int f = 0; f < 4; ++f) {
      const unsigned char* rb = &Bs[(wc * 64 + f * 16 + l15) * BKB];
      i32x4 blo = *(const i32x4*)(rb + (((quad * 2 + 0) ^ r7) * 16));
      i32x4 bhi = *(const i32x4*)(rb + (((quad * 2 + 1) ^ r7) * 16));
      bf[f] = (i32x8){blo.x, blo.y, blo.z, blo.w, bhi.x, bhi.y, bhi.z, bhi.w};
    }
#pragma unroll
    for (int fr = 0; fr < 4; ++fr)
#pragma unroll
      for (int fc = 0; fc < 4; ++fc)
        acc[fr][fc] = __builtin_amdgcn_mfma_scale_f32_16x16x128_f8f6f4(
            af[fr], bf[fc], acc[fr][fc],
            0, 0,                     // cbsz=FP8(e4m3), blgp=FP8(e4m3)
            0, 0x7F7F7F7F,            // opsel_a, scale_a (e8m0 127 = 1.0)
            0, 0x7F7F7F7F);           // opsel_b, scale_b
    __syncthreads();
  }

  // ---- epilogue (R1-validated mapping; acc * 1/256 undoes the 16*16 prescale)
  if (bi == bj && wr == wc && (l15 >> 2) == quad) {
    int r = l15 & 3;
#pragma unroll
    for (int f = 0; f < 4; ++f)
      __hip_atomic_store(&diagv[bi * BT + wr * 64 + f * 16 + l15],
                         acc[f][f][r] * INV256,
                         __ATOMIC_RELAXED, __HIP_MEMORY_SCOPE_AGENT);
  }

  float racc[4][4];
  float cacc[4];
#pragma unroll
  for (int i = 0; i < 4; ++i) {
    cacc[i] = 0.f;
#pragma unroll
    for (int j = 0; j < 4; ++j) racc[i][j] = 0.f;
  }
#pragma unroll
  for (int fr = 0; fr < 4; ++fr)
#pragma unroll
    for (int fc = 0; fc < 4; ++fc) {
      f32x4 v = acc[fr][fc];
#pragma unroll
      for (int r = 0; r < 4; ++r) {
        float e = __expf(v[r] * INV256);
        racc[fr][r] += e;
        cacc[fc]    += e;
      }
    }
#pragma unroll
  for (int m = 1; m <= 8; m <<= 1)
#pragma unroll
    for (int fr = 0; fr < 4; ++fr)
#pragma unroll
      for (int r = 0; r < 4; ++r) racc[fr][r] += __shfl_xor(racc[fr][r], m, 64);
  if (l15 == 0)
#pragma unroll
    for (int fr = 0; fr < 4; ++fr)
#pragma unroll
      for (int r = 0; r < 4; ++r)
        atomicAdd(&red_row[wr * 64 + fr * 16 + quad * 4 + r], racc[fr][r]);
#pragma unroll
  for (int m = 16; m <= 32; m <<= 1)
#pragma unroll
    for (int fc = 0; fc < 4; ++fc) cacc[fc] += __shfl_xor(cacc[fc], m, 64);
  if (quad == 0)
#pragma unroll
    for (int fc = 0; fc < 4; ++fc)
      atomicAdd(&red_col[wc * 64 + fc * 16 + l15], cacc[fc]);

  __syncthreads();
  if (tid < BT) atomicAdd(&rowsum[bi * BT + tid], red_row[tid]);
  else          atomicAdd(&colsum[bj * BT + (tid - BT)], red_col[tid - BT]);

  // ---- last-block-done finalize (validated in R5: absmax 0.0) --------------
  __threadfence();                       // release our atomics before count
  if (tid == 0) {
    unsigned int c = atomicAdd(counter, 1u);
    lastflag = (c == (unsigned int)(NBLK * NBLK - 1));
  }
  __syncthreads();
  if (lastflag) {
    __threadfence();                     // acquire all blocks' results
    float s = 0.f;
    for (int i = tid; i < NROWS; i += 256) {
      float d  = __hip_atomic_load(&diagv[i],  __ATOMIC_RELAXED, __HIP_MEMORY_SCOPE_AGENT);
      float rs = __hip_atomic_load(&rowsum[i], __ATOMIC_RELAXED, __HIP_MEMORY_SCOPE_AGENT);
      float cs = __hip_atomic_load(&colsum[i], __ATOMIC_RELAXED, __HIP_MEMORY_SCOPE_AGENT);
      float ed = __expf(d);
      float m1 = __expf(d - MARGIN);
      s += __logf((m1 + (rs - ed)) / m1) + __logf((m1 + (cs - ed)) / m1);
    }
#pragma unroll
    for (int m = 1; m < 64; m <<= 1) s += __shfl_xor(s, m, 64);
    if ((tid & 63) == 0) red_row[tid >> 6] = s;
    __syncthreads();
    if (tid == 0)
      out[0] = (red_row[0] + red_row[1] + red_row[2] + red_row[3]) / (float)NROWS;
  }
}

// ============================ FALLBACK PATH (R1, known-good) ================
__global__ __launch_bounds__(256) void norm_kernel(const float* __restrict__ x,
                                                   const float* __restrict__ y,
                                                   float* __restrict__ invn) {
  int wid  = (int)((blockIdx.x * blockDim.x + threadIdx.x) >> 6);
  int lane = threadIdx.x & 63;
  const float* src = (wid < NROWS) ? x : y;
  int row = (wid < NROWS) ? wid : (wid - NROWS);
  const float4* p = (const float4*)(src + (size_t)row * DDIM);
  float s = 0.f;
#pragma unroll
  for (int a = 0; a < 4; ++a) {
    float4 v = p[a * 64 + lane];
    s = fmaf(v.x, v.x, s); s = fmaf(v.y, v.y, s);
    s = fmaf(v.z, v.z, s); s = fmaf(v.w, v.w, s);
  }
#pragma unroll
  for (int m = 1; m < 64; m <<= 1) s += __shfl_xor(s, m, 64);
  if (lane == 0) invn[wid] = 1.0f / fmaxf(sqrtf(s), 1e-8f);
}

__global__ __launch_bounds__(256) void gemm_kernel(const float* __restrict__ x,
                                                   const float* __restrict__ y,
                                                   const float* __restrict__ invn,
                                                   float* __restrict__ rowsum,
                                                   float* __restrict__ colsum,
                                                   float* __restrict__ diagv) {
  __shared__ alignas(16) unsigned short As[BT * 64];
  __shared__ alignas(16) unsigned short Bs[BT * 64];
  __shared__ float red_row[BT];
  __shared__ float red_col[BT];

  const int tid  = threadIdx.x;
  const int bi   = blockIdx.y;
  const int bj   = blockIdx.x;
  const int lane = tid & 63;
  const int wave = tid >> 6;
  const int wr   = wave >> 1, wc = wave & 1;
  const int quad = lane >> 4, l15 = lane & 15;
  const int srow = tid >> 4;
  const int sc4  = tid & 15;

  if (tid < BT) red_row[tid] = 0.f; else red_col[tid - BT] = 0.f;

  float ainv[8], binv[8];
#pragma unroll
  for (int a = 0; a < 8; ++a) {
    ainv[a] = invn[bi * BT + a * 16 + srow];
    binv[a] = invn[NROWS + bj * BT + a * 16 + srow];
  }

  f32x4 acc[4][4];
#pragma unroll
  for (int i = 0; i < 4; ++i)
#pragma unroll
    for (int j = 0; j < 4; ++j) acc[i][j] = (f32x4){0.f, 0.f, 0.f, 0.f};

  for (int k0 = 0; k0 < DDIM; k0 += 64) {
#pragma unroll
    for (int a = 0; a < 8; ++a) {
      int row = a * 16 + srow;
      float4 va = *(const float4*)(x + (size_t)(bi * BT + row) * DDIM + k0 + sc4 * 4);
      float4 vb = *(const float4*)(y + (size_t)(bj * BT + row) * DDIM + k0 + sc4 * 4);
      float sa = ainv[a], sb = binv[a];
      unsigned long long pa =
          (unsigned long long)f2bf_bits(va.x * sa) |
          ((unsigned long long)f2bf_bits(va.y * sa) << 16) |
          ((unsigned long long)f2bf_bits(va.z * sa) << 32) |
          ((unsigned long long)f2bf_bits(va.w * sa) << 48);
      unsigned long long pb =
          (unsigned long long)f2bf_bits(vb.x * sb) |
          ((unsigned long long)f2bf_bits(vb.y * sb) << 16) |
          ((unsigned long long)f2bf_bits(vb.z * sb) << 32) |
          ((unsigned long long)f2bf_bits(vb.w * sb) << 48);
      *(unsigned long long*)&As[row * 64 + sc4 * 4] = pa;
      *(unsigned long long*)&Bs[row * 64 + sc4 * 4] = pb;
    }
    __syncthreads();
#pragma unroll
    for (int kk = 0; kk < 64; kk += 32) {
      bf16x8 af[4], bf[4];
#pragma unroll
      for (int f = 0; f < 4; ++f) {
        af[f] = *(const bf16x8*)&As[(wr * 64 + f * 16 + l15) * 64 + kk + quad * 8];
        bf[f] = *(const bf16x8*)&Bs[(wc * 64 + f * 16 + l15) * 64 + kk + quad * 8];
      }
#pragma unroll
      for (int fr = 0; fr < 4; ++fr)
#pragma unroll
        for (int fc = 0; fc < 4; ++fc)
          acc[fr][fc] = __builtin_amdgcn_mfma_f32_16x16x32_bf16(af[fr], bf[fc], acc[fr][fc], 0, 0, 0);
    }
    __syncthreads();
  }

  if (bi == bj && wr == wc && (l15 >> 2) == quad) {
    int r = l15 & 3;
#pragma unroll
    for (int f = 0; f < 4; ++f)
      diagv[bi * BT + wr * 64 + f * 16 + l15] = acc[f][f][r];
  }

  float racc[4][4];
  float cacc[4];
#pragma unroll
  for (int i = 0; i < 4; ++i) {
    cacc[i] = 0.f;
#pragma unroll
    for (int j = 0; j < 4; ++j) racc[i][j] = 0.f;
  }
#pragma unroll
  for (int fr = 0; fr < 4; ++fr)
#pragma unroll
    for (int fc = 0; fc < 4; ++fc) {
      f32x4 v = acc[fr][fc];
#pragma unroll
      for (int r = 0; r < 4; ++r) {
        float e = __expf(v[r]);
        racc[fr][r] += e;
        cacc[fc]    += e;
      }
    }
#pragma unroll
  for (int m = 1; m <= 8; m <<= 1)
#pragma unroll
    for (int fr = 0; fr < 4; ++fr)
#pragma unroll
      for (int r = 0; r < 4; ++r) racc[fr][r] += __shfl_xor(racc[fr][r], m, 64);
  if (l15 == 0)
#pragma unroll
    for (int fr = 0; fr < 4; ++fr)
#pragma unroll
      for (int r = 0; r < 4; ++r)
        atomicAdd(&red_row[wr * 64 + fr * 16 + quad * 4 + r], racc[fr][r]);
#pragma unroll
  for (int m = 16; m <= 32; m <<= 1)
#pragma unroll
    for (int fc = 0; fc < 4; ++fc) cacc[fc] += __shfl_xor(cacc[fc], m, 64);
  if (quad == 0)
#pragma unroll
    for (int fc = 0; fc < 4; ++fc)
      atomicAdd(&red_col[wc * 64 + fc * 16 + l15], cacc[fc]);

  __syncthreads();
  if (tid < BT) atomicAdd(&rowsum[bi * BT + tid], red_row[tid]);
  else          atomicAdd(&colsum[bj * BT + (tid - BT)], red_col[tid - BT]);
}

__global__ __launch_bounds__(1024) void finalize_kernel(const float* __restrict__ rowsum,
                                                        const float* __restrict__ colsum,
                                                        const float* __restrict__ diagv,
                                                        float* __restrict__ out) {
  float s = 0.f;
  for (int i = threadIdx.x; i < NROWS; i += 1024) {
    float d  = diagv[i];
    float ed = __expf(d);
    float m1 = __expf(d - MARGIN);
    float negR = rowsum[i] - ed;
    float negC = colsum[i] - ed;
    s += __logf((m1 + negR) / m1) + __logf((m1 + negC) / m1);
  }
  __shared__ float red[16];
#pragma unroll
  for (int m = 1; m < 64; m <<= 1) s += __shfl_xor(s, m, 64);
  if ((threadIdx.x & 63) == 0) red[threadIdx.x >> 6] = s;
  __syncthreads();
  if (threadIdx.x < 64) {
    float v = (threadIdx.x < 16) ? red[threadIdx.x] : 0.f;
#pragma unroll
    for (int m = 1; m < 16; m <<= 1) v += __shfl_xor(v, m, 64);
    if (threadIdx.x == 0) out[0] = v / (float)NROWS;
  }
}

extern "C" void kernel_launch(void* const* d_in, const int* in_sizes, int n_in,
                              void* d_out, int out_size, void* d_ws, size_t ws_size,
                              hipStream_t stream) {
  const float* x = (const float*)d_in[0];
  const float* y = (const float*)d_in[1];
  float* out = (float*)d_out;
  char* ws = (char*)d_ws;

  const size_t q_bytes = (size_t)NROWS * DDIM;               // 8 MB each (fp8)
  const size_t need_fast = 2 * q_bytes + 3 * NROWS * 4 + 64; // ~16 MB + 96 KB

  if (ws_size >= need_fast) {
    unsigned int* xqF = (unsigned int*)ws;
    unsigned int* yq  = (unsigned int*)(ws + q_bytes);
    float* rowsum = (float*)(ws + 2 * q_bytes);
    float* colsum = rowsum + NROWS;
    float* diagv  = colsum + NROWS;
    unsigned int* counter = (unsigned int*)(diagv + NROWS);
    normconv8_kernel<<<dim3((2 * NROWS) / 4), 256, 0, stream>>>(x, y, xqF, yq, rowsum, counter);
    gemm_mx_kernel<<<dim3(NBLK, NBLK), 256, 0, stream>>>(
        (const unsigned char*)xqF, (const unsigned char*)yq, rowsum, colsum, diagv, counter, out);
  } else {
    float* invn   = (float*)ws;
    float* rowsum = (float*)(ws + 16384 * 4);
    float* colsum = rowsum + NROWS;
    float* diagv  = colsum + NROWS;
    hipMemsetAsync(rowsum, 0, 2 * NROWS * sizeof(float), stream);
    norm_kernel<<<dim3((2 * NROWS) / 4 / 64), 256, 0, stream>>>(x, y, invn);
    gemm_kernel<<<dim3(NROWS / BT, NROWS / BT), 256, 0, stream>>>(x, y, invn, rowsum, colsum, diagv);
    finalize_kernel<<<dim3(1), 1024, 0, stream>>>(rowsum, colsum, diagv, out);
  }
}

// Round 7
// 392.529 us; speedup vs baseline: 1.2273x; 1.0489x over previous
//
#include <hip/hip_runtime.h>
#include <hip/hip_bf16.h>
#include <math.h>

#define NROWS 8192
#define DDIM  1024
#define BT    128
#define NBLK  (NROWS / BT)
#define MARGIN 0.3f
#define INV1024 0.0009765625f

typedef __attribute__((ext_vector_type(4))) float  f32x4;
typedef __attribute__((ext_vector_type(8))) __bf16 bf16x8;
typedef __attribute__((ext_vector_type(4))) int    i32x4;
typedef __attribute__((ext_vector_type(8))) int    i32x8;

__device__ __forceinline__ unsigned f2bf_bits(float f) {
  unsigned u = __float_as_uint(f);
  u += 0x7fffu + ((u >> 16) & 1u);   // RNE
  return u >> 16;
}

// fp4 e2m1 quantize of u (|u| up to ~6, saturating): 3-bit magnitude code is
// monotonic over levels {0,0.5,1,1.5,2,3,4,6} -> compare ladder.
__device__ __forceinline__ unsigned q4(float u) {
  float a = fabsf(u);
  unsigned c = (unsigned)(a > 0.25f) + (unsigned)(a > 0.75f) + (unsigned)(a > 1.25f)
             + (unsigned)(a > 1.75f) + (unsigned)(a > 2.5f)  + (unsigned)(a > 3.5f)
             + (unsigned)(a > 5.0f);
  return c | ((__float_as_uint(u) >> 28) & 8u);   // sign -> bit 3
}

// ============================ FAST PATH (MX-fp4) ============================
// Kernel A: row-norm + fp4 e2m1 quantize of 32*xn (row-major, 512 B/row);
// zeroes rowsum/colsum and the completion counter.
__global__ __launch_bounds__(256) void normconv4_kernel(const float* __restrict__ x,
                                                        const float* __restrict__ y,
                                                        unsigned short* __restrict__ xq4,
                                                        unsigned short* __restrict__ yq4,
                                                        float* __restrict__ zero_base,
                                                        unsigned int* __restrict__ counter) {
  if (blockIdx.x < 16) {  // 16 blk * 256 thr * float4 = 16384 floats (rowsum+colsum)
    ((float4*)zero_base)[blockIdx.x * 256 + threadIdx.x] = (float4){0.f, 0.f, 0.f, 0.f};
  }
  if (blockIdx.x == 16 && threadIdx.x == 0) *counter = 0u;
  int wid  = blockIdx.x * 4 + (threadIdx.x >> 6);   // one wave per row
  int lane = threadIdx.x & 63;
  bool isx = (wid < NROWS);
  const float* src = isx ? x : y;
  unsigned short* dst = isx ? xq4 : yq4;
  int row = isx ? wid : (wid - NROWS);
  const float4* p = (const float4*)(src + (size_t)row * DDIM);
  float4 v[4];
  float s = 0.f;
#pragma unroll
  for (int a = 0; a < 4; ++a) {
    v[a] = p[a * 64 + lane];
    s = fmaf(v[a].x, v[a].x, s); s = fmaf(v[a].y, v[a].y, s);
    s = fmaf(v[a].z, v[a].z, s); s = fmaf(v[a].w, v[a].w, s);
  }
#pragma unroll
  for (int m = 1; m < 64; m <<= 1) s += __shfl_xor(s, m, 64);
  // scale by 32: xn*32 ~ N(0,1), fp4 range +-6 clips at ~6 sigma. Undone by
  // 1/1024 on the accumulator in the gemm epilogue.
  float inv = 32.0f / fmaxf(sqrtf(s), 1e-8f);
  unsigned short* drow = dst + (size_t)row * 256;  // 512 B/row as ushort
#pragma unroll
  for (int a = 0; a < 4; ++a) {
    unsigned n0 = q4(v[a].x * inv), n1 = q4(v[a].y * inv);
    unsigned n2 = q4(v[a].z * inv), n3 = q4(v[a].w * inv);
    drow[a * 64 + lane] = (unsigned short)(n0 | (n1 << 4) | (n2 << 8) | (n3 << 12));
  }
}

// Kernel B: MX-fp4 GEMM (16x16x128 f8f6f4, FMT=fp4, scales=1.0). Both A and B
// staged via global_load_lds (R4-validated structure); 64-B rows with XOR bank
// swizzle: physical 16B-group p = logical g ^ ((row>>1)&3) -> 2-way (free).
// Fused exp + row/col reduce + diag epilogue; last-block-done finalize.
__global__ __launch_bounds__(256) void gemm_mx4_kernel(const unsigned char* __restrict__ xq4,
                                                       const unsigned char* __restrict__ yq4,
                                                       float* __restrict__ rowsum,
                                                       float* __restrict__ colsum,
                                                       float* __restrict__ diagv,
                                                       unsigned int* __restrict__ counter,
                                                       float* __restrict__ out) {
  __shared__ alignas(16) unsigned char As[BT * 64];  // 8 KB (fp4: 64 B/row-tile)
  __shared__ alignas(16) unsigned char Bs[BT * 64];  // 8 KB
  __shared__ float red_row[BT];
  __shared__ float red_col[BT];
  __shared__ int lastflag;

  const int tid  = threadIdx.x;
  const int bi   = blockIdx.y;
  const int bj   = blockIdx.x;
  const int lane = tid & 63;
  const int wave = tid >> 6;
  const int wr   = wave >> 1, wc = wave & 1;
  const int quad = lane >> 4, l15 = lane & 15;

  if (tid < BT) red_row[tid] = 0.f; else red_col[tid - BT] = 0.f;

  // staging: each 1024-B DMA issue covers 16 rows x 64 B; lane l -> local row
  // (l>>2), physical group (l&3); SOURCE logical group (l&3)^((l>>3)&3) since
  // local row = wave*32 + a*16 + (l>>2) and ((row>>1)&3) == ((l>>3)&3).
  const int r_l = lane >> 2;
  const int cg  = (lane & 3) ^ ((lane >> 3) & 3);
  const unsigned char* ga = xq4 + (size_t)(bi * BT + wave * 32 + r_l) * 512 + cg * 16;
  const unsigned char* gb = yq4 + (size_t)(bj * BT + wave * 32 + r_l) * 512 + cg * 16;

  f32x4 acc[4][4];
#pragma unroll
  for (int i = 0; i < 4; ++i)
#pragma unroll
    for (int j = 0; j < 4; ++j) acc[i][j] = (f32x4){0.f, 0.f, 0.f, 0.f};

  const int pg = (quad ^ ((l15 >> 1) & 3)) * 16;   // physical 16B-group offset
  for (int k0 = 0; k0 < DDIM; k0 += 128) {
    const int kb = k0 >> 1;                        // byte offset within row
#pragma unroll
    for (int a = 0; a < 2; ++a) {
      __builtin_amdgcn_global_load_lds(
          (const __attribute__((address_space(1))) unsigned int*)(ga + (size_t)a * 16 * 512 + kb),
          (__attribute__((address_space(3))) unsigned int*)&As[(wave * 32 + a * 16) * 64],
          16, 0, 0);
      __builtin_amdgcn_global_load_lds(
          (const __attribute__((address_space(1))) unsigned int*)(gb + (size_t)a * 16 * 512 + kb),
          (__attribute__((address_space(3))) unsigned int*)&Bs[(wave * 32 + a * 16) * 64],
          16, 0, 0);
    }
    __syncthreads();
    i32x8 af[4], bf[4];
#pragma unroll
    for (int f = 0; f < 4; ++f) {
      i32x4 a4 = *(const i32x4*)&As[(wr * 64 + f * 16 + l15) * 64 + pg];
      i32x4 b4 = *(const i32x4*)&Bs[(wc * 64 + f * 16 + l15) * 64 + pg];
      af[f] = (i32x8){a4.x, a4.y, a4.z, a4.w, 0, 0, 0, 0};  // fp4: low 4 regs
      bf[f] = (i32x8){b4.x, b4.y, b4.z, b4.w, 0, 0, 0, 0};
    }
#pragma unroll
    for (int fr = 0; fr < 4; ++fr)
#pragma unroll
      for (int fc = 0; fc < 4; ++fc)
        acc[fr][fc] = __builtin_amdgcn_mfma_scale_f32_16x16x128_f8f6f4(
            af[fr], bf[fc], acc[fr][fc],
            4, 4,                     // cbsz=FP4(e2m1), blgp=FP4(e2m1)
            0, 0x7F7F7F7F,            // opsel_a, scale_a (e8m0 127 = 1.0)
            0, 0x7F7F7F7F);           // opsel_b, scale_b
    __syncthreads();
  }

  // ---- epilogue (R1-validated mapping; 1/1024 undoes the 32*32 prescale) ---
  if (bi == bj && wr == wc && (l15 >> 2) == quad) {
    int r = l15 & 3;
#pragma unroll
    for (int f = 0; f < 4; ++f)
      __hip_atomic_store(&diagv[bi * BT + wr * 64 + f * 16 + l15],
                         acc[f][f][r] * INV1024,
                         __ATOMIC_RELAXED, __HIP_MEMORY_SCOPE_AGENT);
  }

  float racc[4][4];
  float cacc[4];
#pragma unroll
  for (int i = 0; i < 4; ++i) {
    cacc[i] = 0.f;
#pragma unroll
    for (int j = 0; j < 4; ++j) racc[i][j] = 0.f;
  }
#pragma unroll
  for (int fr = 0; fr < 4; ++fr)
#pragma unroll
    for (int fc = 0; fc < 4; ++fc) {
      f32x4 v = acc[fr][fc];
#pragma unroll
      for (int r = 0; r < 4; ++r) {
        float e = __expf(v[r] * INV1024);
        racc[fr][r] += e;
        cacc[fc]    += e;
      }
    }
#pragma unroll
  for (int m = 1; m <= 8; m <<= 1)
#pragma unroll
    for (int fr = 0; fr < 4; ++fr)
#pragma unroll
      for (int r = 0; r < 4; ++r) racc[fr][r] += __shfl_xor(racc[fr][r], m, 64);
  if (l15 == 0)
#pragma unroll
    for (int fr = 0; fr < 4; ++fr)
#pragma unroll
      for (int r = 0; r < 4; ++r)
        atomicAdd(&red_row[wr * 64 + fr * 16 + quad * 4 + r], racc[fr][r]);
#pragma unroll
  for (int m = 16; m <= 32; m <<= 1)
#pragma unroll
    for (int fc = 0; fc < 4; ++fc) cacc[fc] += __shfl_xor(cacc[fc], m, 64);
  if (quad == 0)
#pragma unroll
    for (int fc = 0; fc < 4; ++fc)
      atomicAdd(&red_col[wc * 64 + fc * 16 + l15], cacc[fc]);

  __syncthreads();
  if (tid < BT) atomicAdd(&rowsum[bi * BT + tid], red_row[tid]);
  else          atomicAdd(&colsum[bj * BT + (tid - BT)], red_col[tid - BT]);

  // ---- last-block-done finalize (validated R5/R6: absmax 0.0) --------------
  __threadfence();
  if (tid == 0) {
    unsigned int c = atomicAdd(counter, 1u);
    lastflag = (c == (unsigned int)(NBLK * NBLK - 1));
  }
  __syncthreads();
  if (lastflag) {
    __threadfence();
    float s = 0.f;
    for (int i = tid; i < NROWS; i += 256) {
      float d  = __hip_atomic_load(&diagv[i],  __ATOMIC_RELAXED, __HIP_MEMORY_SCOPE_AGENT);
      float rs = __hip_atomic_load(&rowsum[i], __ATOMIC_RELAXED, __HIP_MEMORY_SCOPE_AGENT);
      float cs = __hip_atomic_load(&colsum[i], __ATOMIC_RELAXED, __HIP_MEMORY_SCOPE_AGENT);
      float ed = __expf(d);
      float m1 = __expf(d - MARGIN);
      s += __logf((m1 + (rs - ed)) / m1) + __logf((m1 + (cs - ed)) / m1);
    }
#pragma unroll
    for (int m = 1; m < 64; m <<= 1) s += __shfl_xor(s, m, 64);
    if ((tid & 63) == 0) red_row[tid >> 6] = s;
    __syncthreads();
    if (tid == 0)
      out[0] = (red_row[0] + red_row[1] + red_row[2] + red_row[3]) / (float)NROWS;
  }
}

// ============================ FALLBACK PATH (R1, known-good) ================
__global__ __launch_bounds__(256) void norm_kernel(const float* __restrict__ x,
                                                   const float* __restrict__ y,
                                                   float* __restrict__ invn) {
  int wid  = (int)((blockIdx.x * blockDim.x + threadIdx.x) >> 6);
  int lane = threadIdx.x & 63;
  const float* src = (wid < NROWS) ? x : y;
  int row = (wid < NROWS) ? wid : (wid - NROWS);
  const float4* p = (const float4*)(src + (size_t)row * DDIM);
  float s = 0.f;
#pragma unroll
  for (int a = 0; a < 4; ++a) {
    float4 v = p[a * 64 + lane];
    s = fmaf(v.x, v.x, s); s = fmaf(v.y, v.y, s);
    s = fmaf(v.z, v.z, s); s = fmaf(v.w, v.w, s);
  }
#pragma unroll
  for (int m = 1; m < 64; m <<= 1) s += __shfl_xor(s, m, 64);
  if (lane == 0) invn[wid] = 1.0f / fmaxf(sqrtf(s), 1e-8f);
}

__global__ __launch_bounds__(256) void gemm_kernel(const float* __restrict__ x,
                                                   const float* __restrict__ y,
                                                   const float* __restrict__ invn,
                                                   float* __restrict__ rowsum,
                                                   float* __restrict__ colsum,
                                                   float* __restrict__ diagv) {
  __shared__ alignas(16) unsigned short As[BT * 64];
  __shared__ alignas(16) unsigned short Bs[BT * 64];
  __shared__ float red_row[BT];
  __shared__ float red_col[BT];

  const int tid  = threadIdx.x;
  const int bi   = blockIdx.y;
  const int bj   = blockIdx.x;
  const int lane = tid & 63;
  const int wave = tid >> 6;
  const int wr   = wave >> 1, wc = wave & 1;
  const int quad = lane >> 4, l15 = lane & 15;
  const int srow = tid >> 4;
  const int sc4  = tid & 15;

  if (tid < BT) red_row[tid] = 0.f; else red_col[tid - BT] = 0.f;

  float ainv[8], binv[8];
#pragma unroll
  for (int a = 0; a < 8; ++a) {
    ainv[a] = invn[bi * BT + a * 16 + srow];
    binv[a] = invn[NROWS + bj * BT + a * 16 + srow];
  }

  f32x4 acc[4][4];
#pragma unroll
  for (int i = 0; i < 4; ++i)
#pragma unroll
    for (int j = 0; j < 4; ++j) acc[i][j] = (f32x4){0.f, 0.f, 0.f, 0.f};

  for (int k0 = 0; k0 < DDIM; k0 += 64) {
#pragma unroll
    for (int a = 0; a < 8; ++a) {
      int row = a * 16 + srow;
      float4 va = *(const float4*)(x + (size_t)(bi * BT + row) * DDIM + k0 + sc4 * 4);
      float4 vb = *(const float4*)(y + (size_t)(bj * BT + row) * DDIM + k0 + sc4 * 4);
      float sa = ainv[a], sb = binv[a];
      unsigned long long pa =
          (unsigned long long)f2bf_bits(va.x * sa) |
          ((unsigned long long)f2bf_bits(va.y * sa) << 16) |
          ((unsigned long long)f2bf_bits(va.z * sa) << 32) |
          ((unsigned long long)f2bf_bits(va.w * sa) << 48);
      unsigned long long pb =
          (unsigned long long)f2bf_bits(vb.x * sb) |
          ((unsigned long long)f2bf_bits(vb.y * sb) << 16) |
          ((unsigned long long)f2bf_bits(vb.z * sb) << 32) |
          ((unsigned long long)f2bf_bits(vb.w * sb) << 48);
      *(unsigned long long*)&As[row * 64 + sc4 * 4] = pa;
      *(unsigned long long*)&Bs[row * 64 + sc4 * 4] = pb;
    }
    __syncthreads();
#pragma unroll
    for (int kk = 0; kk < 64; kk += 32) {
      bf16x8 af[4], bf[4];
#pragma unroll
      for (int f = 0; f < 4; ++f) {
        af[f] = *(const bf16x8*)&As[(wr * 64 + f * 16 + l15) * 64 + kk + quad * 8];
        bf[f] = *(const bf16x8*)&Bs[(wc * 64 + f * 16 + l15) * 64 + kk + quad * 8];
      }
#pragma unroll
      for (int fr = 0; fr < 4; ++fr)
#pragma unroll
        for (int fc = 0; fc < 4; ++fc)
          acc[fr][fc] = __builtin_amdgcn_mfma_f32_16x16x32_bf16(af[fr], bf[fc], acc[fr][fc], 0, 0, 0);
    }
    __syncthreads();
  }

  if (bi == bj && wr == wc && (l15 >> 2) == quad) {
    int r = l15 & 3;
#pragma unroll
    for (int f = 0; f < 4; ++f)
      diagv[bi * BT + wr * 64 + f * 16 + l15] = acc[f][f][r];
  }

  float racc[4][4];
  float cacc[4];
#pragma unroll
  for (int i = 0; i < 4; ++i) {
    cacc[i] = 0.f;
#pragma unroll
    for (int j = 0; j < 4; ++j) racc[i][j] = 0.f;
  }
#pragma unroll
  for (int fr = 0; fr < 4; ++fr)
#pragma unroll
    for (int fc = 0; fc < 4; ++fc) {
      f32x4 v = acc[fr][fc];
#pragma unroll
      for (int r = 0; r < 4; ++r) {
        float e = __expf(v[r]);
        racc[fr][r] += e;
        cacc[fc]    += e;
      }
    }
#pragma unroll
  for (int m = 1; m <= 8; m <<= 1)
#pragma unroll
    for (int fr = 0; fr < 4; ++fr)
#pragma unroll
      for (int r = 0; r < 4; ++r) racc[fr][r] += __shfl_xor(racc[fr][r], m, 64);
  if (l15 == 0)
#pragma unroll
    for (int fr = 0; fr < 4; ++fr)
#pragma unroll
      for (int r = 0; r < 4; ++r)
        atomicAdd(&red_row[wr * 64 + fr * 16 + quad * 4 + r], racc[fr][r]);
#pragma unroll
  for (int m = 16; m <= 32; m <<= 1)
#pragma unroll
    for (int fc = 0; fc < 4; ++fc) cacc[fc] += __shfl_xor(cacc[fc], m, 64);
  if (quad == 0)
#pragma unroll
    for (int fc = 0; fc < 4; ++fc)
      atomicAdd(&red_col[wc * 64 + fc * 16 + l15], cacc[fc]);

  __syncthreads();
  if (tid < BT) atomicAdd(&rowsum[bi * BT + tid], red_row[tid]);
  else          atomicAdd(&colsum[bj * BT + (tid - BT)], red_col[tid - BT]);
}

__global__ __launch_bounds__(1024) void finalize_kernel(const float* __restrict__ rowsum,
                                                        const float* __restrict__ colsum,
                                                        const float* __restrict__ diagv,
                                                        float* __restrict__ out) {
  float s = 0.f;
  for (int i = threadIdx.x; i < NROWS; i += 1024) {
    float d  = diagv[i];
    float ed = __expf(d);
    float m1 = __expf(d - MARGIN);
    float negR = rowsum[i] - ed;
    float negC = colsum[i] - ed;
    s += __logf((m1 + negR) / m1) + __logf((m1 + negC) / m1);
  }
  __shared__ float red[16];
#pragma unroll
  for (int m = 1; m < 64; m <<= 1) s += __shfl_xor(s, m, 64);
  if ((threadIdx.x & 63) == 0) red[threadIdx.x >> 6] = s;
  __syncthreads();
  if (threadIdx.x < 64) {
    float v = (threadIdx.x < 16) ? red[threadIdx.x] : 0.f;
#pragma unroll
    for (int m = 1; m < 16; m <<= 1) v += __shfl_xor(v, m, 64);
    if (threadIdx.x == 0) out[0] = v / (float)NROWS;
  }
}

extern "C" void kernel_launch(void* const* d_in, const int* in_sizes, int n_in,
                              void* d_out, int out_size, void* d_ws, size_t ws_size,
                              hipStream_t stream) {
  const float* x = (const float*)d_in[0];
  const float* y = (const float*)d_in[1];
  float* out = (float*)d_out;
  char* ws = (char*)d_ws;

  const size_t q_bytes = (size_t)NROWS * 512;                // 4 MB each (fp4)
  const size_t need_fast = 2 * q_bytes + 3 * NROWS * 4 + 64; // ~8 MB + 96 KB

  if (ws_size >= need_fast) {
    unsigned short* xq4 = (unsigned short*)ws;
    unsigned short* yq4 = (unsigned short*)(ws + q_bytes);
    float* rowsum = (float*)(ws + 2 * q_bytes);
    float* colsum = rowsum + NROWS;
    float* diagv  = colsum + NROWS;
    unsigned int* counter = (unsigned int*)(diagv + NROWS);
    normconv4_kernel<<<dim3((2 * NROWS) / 4), 256, 0, stream>>>(x, y, xq4, yq4, rowsum, counter);
    gemm_mx4_kernel<<<dim3(NBLK, NBLK), 256, 0, stream>>>(
        (const unsigned char*)xq4, (const unsigned char*)yq4, rowsum, colsum, diagv, counter, out);
  } else {
    float* invn   = (float*)ws;
    float* rowsum = (float*)(ws + 16384 * 4);
    float* colsum = rowsum + NROWS;
    float* diagv  = colsum + NROWS;
    hipMemsetAsync(rowsum, 0, 2 * NROWS * sizeof(float), stream);
    norm_kernel<<<dim3((2 * NROWS) / 4 / 64), 256, 0, stream>>>(x, y, invn);
    gemm_kernel<<<dim3(NROWS / BT, NROWS / BT), 256, 0, stream>>>(x, y, invn, rowsum, colsum, diagv);
    finalize_kernel<<<dim3(1), 1024, 0, stream>>>(rowsum, colsum, diagv, out);
  }
}

// Round 8
// 158.294 us; speedup vs baseline: 3.0434x; 2.4797x over previous
//
#include <hip/hip_runtime.h>
#include <hip/hip_bf16.h>
#include <math.h>

#define NROWS 8192
#define DDIM  1024
#define BT    128
#define NBLK  (NROWS / BT)
#define MARGIN 0.3f
#define INV1024 0.0009765625f

typedef __attribute__((ext_vector_type(4))) float  f32x4;
typedef __attribute__((ext_vector_type(8))) __bf16 bf16x8;
typedef __attribute__((ext_vector_type(4))) int    i32x4;
typedef __attribute__((ext_vector_type(8))) int    i32x8;

__device__ __forceinline__ unsigned f2bf_bits(float f) {
  unsigned u = __float_as_uint(f);
  u += 0x7fffu + ((u >> 16) & 1u);   // RNE
  return u >> 16;
}

// fp4 e2m1 quantize of u (|u| up to ~6, saturating): 3-bit magnitude code is
// monotonic over levels {0,0.5,1,1.5,2,3,4,6} -> compare ladder.
__device__ __forceinline__ unsigned q4(float u) {
  float a = fabsf(u);
  unsigned c = (unsigned)(a > 0.25f) + (unsigned)(a > 0.75f) + (unsigned)(a > 1.25f)
             + (unsigned)(a > 1.75f) + (unsigned)(a > 2.5f)  + (unsigned)(a > 3.5f)
             + (unsigned)(a > 5.0f);
  return c | ((__float_as_uint(u) >> 28) & 8u);   // sign -> bit 3
}

// ============================ FAST PATH (MX-fp4) ============================
// Kernel A: row-norm + fp4 e2m1 quantize of 32*xn (row-major, 512 B/row);
// zeroes rowsum/colsum.
__global__ __launch_bounds__(256) void normconv4_kernel(const float* __restrict__ x,
                                                        const float* __restrict__ y,
                                                        unsigned short* __restrict__ xq4,
                                                        unsigned short* __restrict__ yq4,
                                                        float* __restrict__ zero_base) {
  if (blockIdx.x < 16) {  // 16 blk * 256 thr * float4 = 16384 floats (rowsum+colsum)
    ((float4*)zero_base)[blockIdx.x * 256 + threadIdx.x] = (float4){0.f, 0.f, 0.f, 0.f};
  }
  int wid  = blockIdx.x * 4 + (threadIdx.x >> 6);   // one wave per row
  int lane = threadIdx.x & 63;
  bool isx = (wid < NROWS);
  const float* src = isx ? x : y;
  unsigned short* dst = isx ? xq4 : yq4;
  int row = isx ? wid : (wid - NROWS);
  const float4* p = (const float4*)(src + (size_t)row * DDIM);
  float4 v[4];
  float s = 0.f;
#pragma unroll
  for (int a = 0; a < 4; ++a) {
    v[a] = p[a * 64 + lane];
    s = fmaf(v[a].x, v[a].x, s); s = fmaf(v[a].y, v[a].y, s);
    s = fmaf(v[a].z, v[a].z, s); s = fmaf(v[a].w, v[a].w, s);
  }
#pragma unroll
  for (int m = 1; m < 64; m <<= 1) s += __shfl_xor(s, m, 64);
  // scale by 32: xn*32 ~ N(0,1), fp4 range +-6 clips at ~6 sigma. Undone by
  // 1/1024 on the accumulator in the gemm epilogue.
  float inv = 32.0f / fmaxf(sqrtf(s), 1e-8f);
  unsigned short* drow = dst + (size_t)row * 256;  // 512 B/row as ushort
#pragma unroll
  for (int a = 0; a < 4; ++a) {
    unsigned n0 = q4(v[a].x * inv), n1 = q4(v[a].y * inv);
    unsigned n2 = q4(v[a].z * inv), n3 = q4(v[a].w * inv);
    drow[a * 64 + lane] = (unsigned short)(n0 | (n1 << 4) | (n2 << 8) | (n3 << 12));
  }
}

// Kernel B: MX-fp4 GEMM (16x16x128 f8f6f4, FMT=fp4, scales=1.0). Both A and B
// staged via global_load_lds (R4/R7-validated); 64-B rows, XOR bank swizzle
// (2-way = free, 0 conflicts measured in R7). Fused exp + row/col reduce +
// diag epilogue. NO fused finalize (R7 post-mortem: per-block device fence +
// single-cacheline returning atomics cost ~250 us across 4096 blocks).
__global__ __launch_bounds__(256) void gemm_mx4_kernel(const unsigned char* __restrict__ xq4,
                                                       const unsigned char* __restrict__ yq4,
                                                       float* __restrict__ rowsum,
                                                       float* __restrict__ colsum,
                                                       float* __restrict__ diagv) {
  __shared__ alignas(16) unsigned char As[BT * 64];  // 8 KB (fp4: 64 B/row-tile)
  __shared__ alignas(16) unsigned char Bs[BT * 64];  // 8 KB
  __shared__ float red_row[BT];
  __shared__ float red_col[BT];

  const int tid  = threadIdx.x;
  const int bi   = blockIdx.y;
  const int bj   = blockIdx.x;
  const int lane = tid & 63;
  const int wave = tid >> 6;
  const int wr   = wave >> 1, wc = wave & 1;
  const int quad = lane >> 4, l15 = lane & 15;

  if (tid < BT) red_row[tid] = 0.f; else red_col[tid - BT] = 0.f;

  // staging: each 1024-B DMA issue covers 16 rows x 64 B; lane l -> local row
  // (l>>2), physical group (l&3); SOURCE logical group (l&3)^((l>>3)&3).
  const int r_l = lane >> 2;
  const int cg  = (lane & 3) ^ ((lane >> 3) & 3);
  const unsigned char* ga = xq4 + (size_t)(bi * BT + wave * 32 + r_l) * 512 + cg * 16;
  const unsigned char* gb = yq4 + (size_t)(bj * BT + wave * 32 + r_l) * 512 + cg * 16;

  f32x4 acc[4][4];
#pragma unroll
  for (int i = 0; i < 4; ++i)
#pragma unroll
    for (int j = 0; j < 4; ++j) acc[i][j] = (f32x4){0.f, 0.f, 0.f, 0.f};

  const int pg = (quad ^ ((l15 >> 1) & 3)) * 16;   // physical 16B-group offset
  for (int k0 = 0; k0 < DDIM; k0 += 128) {
    const int kb = k0 >> 1;                        // byte offset within row
#pragma unroll
    for (int a = 0; a < 2; ++a) {
      __builtin_amdgcn_global_load_lds(
          (const __attribute__((address_space(1))) unsigned int*)(ga + (size_t)a * 16 * 512 + kb),
          (__attribute__((address_space(3))) unsigned int*)&As[(wave * 32 + a * 16) * 64],
          16, 0, 0);
      __builtin_amdgcn_global_load_lds(
          (const __attribute__((address_space(1))) unsigned int*)(gb + (size_t)a * 16 * 512 + kb),
          (__attribute__((address_space(3))) unsigned int*)&Bs[(wave * 32 + a * 16) * 64],
          16, 0, 0);
    }
    __syncthreads();
    i32x8 af[4], bf[4];
#pragma unroll
    for (int f = 0; f < 4; ++f) {
      i32x4 a4 = *(const i32x4*)&As[(wr * 64 + f * 16 + l15) * 64 + pg];
      i32x4 b4 = *(const i32x4*)&Bs[(wc * 64 + f * 16 + l15) * 64 + pg];
      af[f] = (i32x8){a4.x, a4.y, a4.z, a4.w, 0, 0, 0, 0};  // fp4: low 4 regs
      bf[f] = (i32x8){b4.x, b4.y, b4.z, b4.w, 0, 0, 0, 0};
    }
#pragma unroll
    for (int fr = 0; fr < 4; ++fr)
#pragma unroll
      for (int fc = 0; fc < 4; ++fc)
        acc[fr][fc] = __builtin_amdgcn_mfma_scale_f32_16x16x128_f8f6f4(
            af[fr], bf[fc], acc[fr][fc],
            4, 4,                     // cbsz=FP4(e2m1), blgp=FP4(e2m1)
            0, 0x7F7F7F7F,            // opsel_a, scale_a (e8m0 127 = 1.0)
            0, 0x7F7F7F7F);           // opsel_b, scale_b
    __syncthreads();
  }

  // ---- epilogue (R1-validated mapping; 1/1024 undoes the 32*32 prescale) ---
  if (bi == bj && wr == wc && (l15 >> 2) == quad) {
    int r = l15 & 3;
#pragma unroll
    for (int f = 0; f < 4; ++f)
      diagv[bi * BT + wr * 64 + f * 16 + l15] = acc[f][f][r] * INV1024;
  }

  float racc[4][4];
  float cacc[4];
#pragma unroll
  for (int i = 0; i < 4; ++i) {
    cacc[i] = 0.f;
#pragma unroll
    for (int j = 0; j < 4; ++j) racc[i][j] = 0.f;
  }
#pragma unroll
  for (int fr = 0; fr < 4; ++fr)
#pragma unroll
    for (int fc = 0; fc < 4; ++fc) {
      f32x4 v = acc[fr][fc];
#pragma unroll
      for (int r = 0; r < 4; ++r) {
        float e = __expf(v[r] * INV1024);
        racc[fr][r] += e;
        cacc[fc]    += e;
      }
    }
#pragma unroll
  for (int m = 1; m <= 8; m <<= 1)
#pragma unroll
    for (int fr = 0; fr < 4; ++fr)
#pragma unroll
      for (int r = 0; r < 4; ++r) racc[fr][r] += __shfl_xor(racc[fr][r], m, 64);
  if (l15 == 0)
#pragma unroll
    for (int fr = 0; fr < 4; ++fr)
#pragma unroll
      for (int r = 0; r < 4; ++r)
        atomicAdd(&red_row[wr * 64 + fr * 16 + quad * 4 + r], racc[fr][r]);
#pragma unroll
  for (int m = 16; m <= 32; m <<= 1)
#pragma unroll
    for (int fc = 0; fc < 4; ++fc) cacc[fc] += __shfl_xor(cacc[fc], m, 64);
  if (quad == 0)
#pragma unroll
    for (int fc = 0; fc < 4; ++fc)
      atomicAdd(&red_col[wc * 64 + fc * 16 + l15], cacc[fc]);

  __syncthreads();
  if (tid < BT) atomicAdd(&rowsum[bi * BT + tid], red_row[tid]);
  else          atomicAdd(&colsum[bj * BT + (tid - BT)], red_col[tid - BT]);
}

// ============================ FALLBACK PATH (R1, known-good) ================
__global__ __launch_bounds__(256) void norm_kernel(const float* __restrict__ x,
                                                   const float* __restrict__ y,
                                                   float* __restrict__ invn) {
  int wid  = (int)((blockIdx.x * blockDim.x + threadIdx.x) >> 6);
  int lane = threadIdx.x & 63;
  const float* src = (wid < NROWS) ? x : y;
  int row = (wid < NROWS) ? wid : (wid - NROWS);
  const float4* p = (const float4*)(src + (size_t)row * DDIM);
  float s = 0.f;
#pragma unroll
  for (int a = 0; a < 4; ++a) {
    float4 v = p[a * 64 + lane];
    s = fmaf(v.x, v.x, s); s = fmaf(v.y, v.y, s);
    s = fmaf(v.z, v.z, s); s = fmaf(v.w, v.w, s);
  }
#pragma unroll
  for (int m = 1; m < 64; m <<= 1) s += __shfl_xor(s, m, 64);
  if (lane == 0) invn[wid] = 1.0f / fmaxf(sqrtf(s), 1e-8f);
}

__global__ __launch_bounds__(256) void gemm_kernel(const float* __restrict__ x,
                                                   const float* __restrict__ y,
                                                   const float* __restrict__ invn,
                                                   float* __restrict__ rowsum,
                                                   float* __restrict__ colsum,
                                                   float* __restrict__ diagv) {
  __shared__ alignas(16) unsigned short As[BT * 64];
  __shared__ alignas(16) unsigned short Bs[BT * 64];
  __shared__ float red_row[BT];
  __shared__ float red_col[BT];

  const int tid  = threadIdx.x;
  const int bi   = blockIdx.y;
  const int bj   = blockIdx.x;
  const int lane = tid & 63;
  const int wave = tid >> 6;
  const int wr   = wave >> 1, wc = wave & 1;
  const int quad = lane >> 4, l15 = lane & 15;
  const int srow = tid >> 4;
  const int sc4  = tid & 15;

  if (tid < BT) red_row[tid] = 0.f; else red_col[tid - BT] = 0.f;

  float ainv[8], binv[8];
#pragma unroll
  for (int a = 0; a < 8; ++a) {
    ainv[a] = invn[bi * BT + a * 16 + srow];
    binv[a] = invn[NROWS + bj * BT + a * 16 + srow];
  }

  f32x4 acc[4][4];
#pragma unroll
  for (int i = 0; i < 4; ++i)
#pragma unroll
    for (int j = 0; j < 4; ++j) acc[i][j] = (f32x4){0.f, 0.f, 0.f, 0.f};

  for (int k0 = 0; k0 < DDIM; k0 += 64) {
#pragma unroll
    for (int a = 0; a < 8; ++a) {
      int row = a * 16 + srow;
      float4 va = *(const float4*)(x + (size_t)(bi * BT + row) * DDIM + k0 + sc4 * 4);
      float4 vb = *(const float4*)(y + (size_t)(bj * BT + row) * DDIM + k0 + sc4 * 4);
      float sa = ainv[a], sb = binv[a];
      unsigned long long pa =
          (unsigned long long)f2bf_bits(va.x * sa) |
          ((unsigned long long)f2bf_bits(va.y * sa) << 16) |
          ((unsigned long long)f2bf_bits(va.z * sa) << 32) |
          ((unsigned long long)f2bf_bits(va.w * sa) << 48);
      unsigned long long pb =
          (unsigned long long)f2bf_bits(vb.x * sb) |
          ((unsigned long long)f2bf_bits(vb.y * sb) << 16) |
          ((unsigned long long)f2bf_bits(vb.z * sb) << 32) |
          ((unsigned long long)f2bf_bits(vb.w * sb) << 48);
      *(unsigned long long*)&As[row * 64 + sc4 * 4] = pa;
      *(unsigned long long*)&Bs[row * 64 + sc4 * 4] = pb;
    }
    __syncthreads();
#pragma unroll
    for (int kk = 0; kk < 64; kk += 32) {
      bf16x8 af[4], bf[4];
#pragma unroll
      for (int f = 0; f < 4; ++f) {
        af[f] = *(const bf16x8*)&As[(wr * 64 + f * 16 + l15) * 64 + kk + quad * 8];
        bf[f] = *(const bf16x8*)&Bs[(wc * 64 + f * 16 + l15) * 64 + kk + quad * 8];
      }
#pragma unroll
      for (int fr = 0; fr < 4; ++fr)
#pragma unroll
        for (int fc = 0; fc < 4; ++fc)
          acc[fr][fc] = __builtin_amdgcn_mfma_f32_16x16x32_bf16(af[fr], bf[fc], acc[fr][fc], 0, 0, 0);
    }
    __syncthreads();
  }

  if (bi == bj && wr == wc && (l15 >> 2) == quad) {
    int r = l15 & 3;
#pragma unroll
    for (int f = 0; f < 4; ++f)
      diagv[bi * BT + wr * 64 + f * 16 + l15] = acc[f][f][r];
  }

  float racc[4][4];
  float cacc[4];
#pragma unroll
  for (int i = 0; i < 4; ++i) {
    cacc[i] = 0.f;
#pragma unroll
    for (int j = 0; j < 4; ++j) racc[i][j] = 0.f;
  }
#pragma unroll
  for (int fr = 0; fr < 4; ++fr)
#pragma unroll
    for (int fc = 0; fc < 4; ++fc) {
      f32x4 v = acc[fr][fc];
#pragma unroll
      for (int r = 0; r < 4; ++r) {
        float e = __expf(v[r]);
        racc[fr][r] += e;
        cacc[fc]    += e;
      }
    }
#pragma unroll
  for (int m = 1; m <= 8; m <<= 1)
#pragma unroll
    for (int fr = 0; fr < 4; ++fr)
#pragma unroll
      for (int r = 0; r < 4; ++r) racc[fr][r] += __shfl_xor(racc[fr][r], m, 64);
  if (l15 == 0)
#pragma unroll
    for (int fr = 0; fr < 4; ++fr)
#pragma unroll
      for (int r = 0; r < 4; ++r)
        atomicAdd(&red_row[wr * 64 + fr * 16 + quad * 4 + r], racc[fr][r]);
#pragma unroll
  for (int m = 16; m <= 32; m <<= 1)
#pragma unroll
    for (int fc = 0; fc < 4; ++fc) cacc[fc] += __shfl_xor(cacc[fc], m, 64);
  if (quad == 0)
#pragma unroll
    for (int fc = 0; fc < 4; ++fc)
      atomicAdd(&red_col[wc * 64 + fc * 16 + l15], cacc[fc]);

  __syncthreads();
  if (tid < BT) atomicAdd(&rowsum[bi * BT + tid], red_row[tid]);
  else          atomicAdd(&colsum[bj * BT + (tid - BT)], red_col[tid - BT]);
}

// ---------------- Final loss (shared by both paths) -------------------------
__global__ __launch_bounds__(1024) void finalize_kernel(const float* __restrict__ rowsum,
                                                        const float* __restrict__ colsum,
                                                        const float* __restrict__ diagv,
                                                        float* __restrict__ out) {
  float s = 0.f;
  for (int i = threadIdx.x; i < NROWS; i += 1024) {
    float d  = diagv[i];
    float ed = __expf(d);
    float m1 = __expf(d - MARGIN);
    float negR = rowsum[i] - ed;
    float negC = colsum[i] - ed;
    s += __logf((m1 + negR) / m1) + __logf((m1 + negC) / m1);
  }
  __shared__ float red[16];
#pragma unroll
  for (int m = 1; m < 64; m <<= 1) s += __shfl_xor(s, m, 64);
  if ((threadIdx.x & 63) == 0) red[threadIdx.x >> 6] = s;
  __syncthreads();
  if (threadIdx.x < 64) {
    float v = (threadIdx.x < 16) ? red[threadIdx.x] : 0.f;
#pragma unroll
    for (int m = 1; m < 16; m <<= 1) v += __shfl_xor(v, m, 64);
    if (threadIdx.x == 0) out[0] = v / (float)NROWS;
  }
}

extern "C" void kernel_launch(void* const* d_in, const int* in_sizes, int n_in,
                              void* d_out, int out_size, void* d_ws, size_t ws_size,
                              hipStream_t stream) {
  const float* x = (const float*)d_in[0];
  const float* y = (const float*)d_in[1];
  float* out = (float*)d_out;
  char* ws = (char*)d_ws;

  const size_t q_bytes = (size_t)NROWS * 512;                // 4 MB each (fp4)
  const size_t need_fast = 2 * q_bytes + 3 * NROWS * 4;      // ~8 MB + 96 KB

  if (ws_size >= need_fast) {
    unsigned short* xq4 = (unsigned short*)ws;
    unsigned short* yq4 = (unsigned short*)(ws + q_bytes);
    float* rowsum = (float*)(ws + 2 * q_bytes);
    float* colsum = rowsum + NROWS;
    float* diagv  = colsum + NROWS;
    normconv4_kernel<<<dim3((2 * NROWS) / 4), 256, 0, stream>>>(x, y, xq4, yq4, rowsum);
    gemm_mx4_kernel<<<dim3(NBLK, NBLK), 256, 0, stream>>>(
        (const unsigned char*)xq4, (const unsigned char*)yq4, rowsum, colsum, diagv);
    finalize_kernel<<<dim3(1), 1024, 0, stream>>>(rowsum, colsum, diagv, out);
  } else {
    float* invn   = (float*)ws;
    float* rowsum = (float*)(ws + 16384 * 4);
    float* colsum = rowsum + NROWS;
    float* diagv  = colsum + NROWS;
    hipMemsetAsync(rowsum, 0, 2 * NROWS * sizeof(float), stream);
    norm_kernel<<<dim3((2 * NROWS) / 4 / 64), 256, 0, stream>>>(x, y, invn);
    gemm_kernel<<<dim3(NROWS / BT, NROWS / BT), 256, 0, stream>>>(x, y, invn, rowsum, colsum, diagv);
    finalize_kernel<<<dim3(1), 1024, 0, stream>>>(rowsum, colsum, diagv, out);
  }
}